// Round 3
// baseline (358.937 us; speedup 1.0000x reference)
//
#include <hip/hip_runtime.h>
#include <math.h>

typedef __bf16 bf16;
typedef __bf16 bf16x4 __attribute__((ext_vector_type(4)));
typedef __bf16 bf16x8 __attribute__((ext_vector_type(8)));
typedef float f32x4 __attribute__((ext_vector_type(4)));

#define MODE_QKV    0
#define MODE_SCORES 1
#define MODE_PV     2

__device__ inline void gload_lds16(const bf16* g, bf16* l) {
    __builtin_amdgcn_global_load_lds(
        (const __attribute__((address_space(1))) void*)g,
        (__attribute__((address_space(3))) void*)l, 16, 0, 0);
}

// NT GEMM, 128x128 tile, BK=32, 4 waves, bf16 in / MFMA 16x16x32.
// MODE_QKV:    C=bf16 qk (ldc), +bias; N-blocks >=2048 write V transposed to Vt[b][e][s].
// MODE_SCORES: C=bf16 Pu = exp(alpha*acc); per-row sums atomicAdd'ed into lsum.
// MODE_PV:     C=fp32, scaled by 1/lsum[row].
template <int MODE>
__global__ __launch_bounds__(256) void mfma_nt(
    const bf16* __restrict__ A, const bf16* __restrict__ B,
    const float* __restrict__ bias, void* __restrict__ Cv,
    bf16* __restrict__ Vt, float* __restrict__ lsum,
    int K, int lda, int ldb, int ldc,
    long sA, long sB, long sC, float alpha)
{
    A += (long)blockIdx.z * sA;
    B += (long)blockIdx.z * sB;
    char* Cb = (char*)Cv + (long)blockIdx.z * sC;
    if constexpr (MODE != MODE_QKV) lsum += (long)blockIdx.z * 2048;

    __shared__ bf16 As[128 * 32] __attribute__((aligned(16)));
    __shared__ bf16 Bs[128 * 32] __attribute__((aligned(16)));

    const int t  = threadIdx.x;
    const int m0 = blockIdx.y * 128;
    const int n0 = blockIdx.x * 128;

    const int lane = t & 63;
    const int wave = t >> 6;
    const int wrow = (wave >> 1) * 64;
    const int wcol = (wave & 1) * 64;
    const int fr   = lane & 15;
    const int kq   = (lane >> 4) * 8;

    const int r0 = t >> 2,           k80 = (t & 3) * 8;
    const int r1 = (t + 256) >> 2,   k81 = ((t + 256) & 3) * 8;

    f32x4 acc[4][4] = {};

    for (int k0 = 0; k0 < K; k0 += 32) {
        gload_lds16(A + (long)(m0 + r0) * lda + k0 + k80, &As[t * 8]);
        gload_lds16(A + (long)(m0 + r1) * lda + k0 + k81, &As[(t + 256) * 8]);
        gload_lds16(B + (long)(n0 + r0) * ldb + k0 + k80, &Bs[t * 8]);
        gload_lds16(B + (long)(n0 + r1) * ldb + k0 + k81, &Bs[(t + 256) * 8]);
        __syncthreads();

        bf16x8 af[4], bfr[4];
#pragma unroll
        for (int i = 0; i < 4; i++) {
            af[i]  = *(const bf16x8*)&As[(wrow + i * 16 + fr) * 32 + kq];
            bfr[i] = *(const bf16x8*)&Bs[(wcol + i * 16 + fr) * 32 + kq];
        }
#pragma unroll
        for (int i = 0; i < 4; i++)
#pragma unroll
            for (int j = 0; j < 4; j++)
                acc[i][j] = __builtin_amdgcn_mfma_f32_16x16x32_bf16(
                    af[i], bfr[j], acc[i][j], 0, 0, 0);
        __syncthreads();
    }

    // C/D layout: col=lane&15, row=(lane>>4)*4+reg  [m89-verified]
    const int r4 = (lane >> 4) * 4;

    if constexpr (MODE == MODE_QKV) {
        if (n0 >= 2048) {
            // V portion -> Vt[b][e][s]; rows (s) are register-consecutive -> 8B stores
#pragma unroll
            for (int j = 0; j < 4; j++) {
                const int col = n0 + wcol + j * 16 + fr;
                const float bv = bias[col];
                const int e = col - 2048;
#pragma unroll
                for (int i = 0; i < 4; i++) {
                    const int row = m0 + wrow + i * 16 + r4;
                    const int b = row >> 11, s = row & 2047;
                    bf16x4 pk;
#pragma unroll
                    for (int r = 0; r < 4; r++) pk[r] = (bf16)(acc[i][j][r] + bv);
                    *(bf16x4*)(Vt + ((long)b * 1024 + e) * 2048 + s) = pk;
                }
            }
        } else {
            bf16* C = (bf16*)Cb;
#pragma unroll
            for (int j = 0; j < 4; j++) {
                const int col = n0 + wcol + j * 16 + fr;
                const float bv = bias[col];
#pragma unroll
                for (int i = 0; i < 4; i++)
#pragma unroll
                    for (int r = 0; r < 4; r++) {
                        const long row = m0 + wrow + i * 16 + r4 + r;
                        C[row * ldc + col] = (bf16)(acc[i][j][r] + bv);
                    }
            }
        }
    } else if constexpr (MODE == MODE_SCORES) {
        bf16* C = (bf16*)Cb;
        float rsum[4][4];
#pragma unroll
        for (int i = 0; i < 4; i++)
#pragma unroll
            for (int r = 0; r < 4; r++) rsum[i][r] = 0.f;
#pragma unroll
        for (int j = 0; j < 4; j++) {
            const int col = n0 + wcol + j * 16 + fr;
#pragma unroll
            for (int i = 0; i < 4; i++)
#pragma unroll
                for (int r = 0; r < 4; r++) {
                    const long row = m0 + wrow + i * 16 + r4 + r;
                    const float e = __expf(alpha * acc[i][j][r]);
                    C[row * ldc + col] = (bf16)e;
                    rsum[i][r] += e;
                }
        }
        // reduce across the 16 fr-lanes (same rows), then one atomic per row-quad
#pragma unroll
        for (int off = 1; off < 16; off <<= 1)
#pragma unroll
            for (int i = 0; i < 4; i++)
#pragma unroll
                for (int r = 0; r < 4; r++)
                    rsum[i][r] += __shfl_xor(rsum[i][r], off);
        if (fr == 0) {
#pragma unroll
            for (int i = 0; i < 4; i++)
#pragma unroll
                for (int r = 0; r < 4; r++)
                    atomicAdd(&lsum[m0 + wrow + i * 16 + r4 + r], rsum[i][r]);
        }
    } else {
        float* C = (float*)Cb;
        float linv[4][4];
#pragma unroll
        for (int i = 0; i < 4; i++)
#pragma unroll
            for (int r = 0; r < 4; r++)
                linv[i][r] = 1.0f / lsum[m0 + wrow + i * 16 + r4 + r];
#pragma unroll
        for (int j = 0; j < 4; j++) {
            const int col = n0 + wcol + j * 16 + fr;
#pragma unroll
            for (int i = 0; i < 4; i++)
#pragma unroll
                for (int r = 0; r < 4; r++) {
                    const long row = m0 + wrow + i * 16 + r4 + r;
                    C[row * ldc + col] = acc[i][j][r] * linv[i][r];
                }
        }
    }
}

__global__ __launch_bounds__(256) void f32_to_bf16(
    const float* __restrict__ in, bf16* __restrict__ out, long n)
{
    long i = ((long)blockIdx.x * 256 + threadIdx.x) * 4;
    if (i < n) {
        float4 v = *(const float4*)(in + i);
        bf16x4 o = { (bf16)v.x, (bf16)v.y, (bf16)v.z, (bf16)v.w };
        *(bf16x4*)(out + i) = o;
    }
}

// out1[row] = fp32(Pu[row]) / l[row]; one block per row, 2048 cols.
__global__ __launch_bounds__(256) void normalize_rows(
    const bf16* __restrict__ Pu, const float* __restrict__ l,
    float* __restrict__ out1)
{
    const long row = blockIdx.x;
    const float inv = 1.0f / l[row];
    const bf16* p = Pu + row * 2048;
    float* o = out1 + row * 2048;
    const int t = threadIdx.x;
    bf16x8 v = *(const bf16x8*)(p + t * 8);
    float4 a, b;
    a.x = (float)v[0] * inv; a.y = (float)v[1] * inv;
    a.z = (float)v[2] * inv; a.w = (float)v[3] * inv;
    b.x = (float)v[4] * inv; b.y = (float)v[5] * inv;
    b.z = (float)v[6] * inv; b.w = (float)v[7] * inv;
    *(float4*)(o + t * 8)     = a;
    *(float4*)(o + t * 8 + 4) = b;
}

extern "C" void kernel_launch(void* const* d_in, const int* in_sizes, int n_in,
                              void* d_out, int out_size, void* d_ws, size_t ws_size,
                              hipStream_t stream)
{
    const int B = 4, S = 2048, E = 1024;
    const float* X    = (const float*)d_in[0];   // [B,S,E]
    const float* W    = (const float*)d_in[1];   // [3E,E]
    const float* bias = (const float*)d_in[2];   // [3E]

    float* out0 = (float*)d_out;                  // [B,S,E]
    float* out1 = out0 + (long)B * S * E;         // [B,S,S]

    // ws layout (bytes; lifetimes annotated):
    //   [ 0M, 32M)  QKb  bf16 [B*S, 2048]  (Q cols 0..1023, K cols 1024..2047)
    //   [32M, 48M)  Vt   bf16 [B][E][S]
    //   [48M, 80M)  Pu   bf16 [B][S][S]    unnormalized exp-scores
    //   [80M, +32K) l    fp32 [B*S]        row sums
    //   Xb/Wb overlap the Pu region (dead before Pu is written)
    char* ws = (char*)d_ws;
    bf16* QKb = (bf16*)(ws);
    bf16* Vt  = (bf16*)(ws + 33554432);
    bf16* Pu  = (bf16*)(ws + 50331648);
    float* l  = (float*)(ws + 83886080);
    bf16* Xb  = (bf16*)(ws + 50331648);
    bf16* Wb  = (bf16*)(ws + 67108864);

    // 1) convert inputs to bf16; zero row-sum accumulator
    f32_to_bf16<<<(long)B * S * E / 1024, 256, 0, stream>>>(X, Xb, (long)B * S * E);
    f32_to_bf16<<<(long)3 * E * E / 1024, 256, 0, stream>>>(W, Wb, (long)3 * E * E);
    hipMemsetAsync(l, 0, (long)B * S * sizeof(float), stream);

    // 2) QKV projection: Q,K -> QKb; V -> Vt (transposed in epilogue)
    mfma_nt<MODE_QKV><<<dim3(3 * E / 128, B * S / 128, 1), 256, 0, stream>>>(
        Xb, Wb, bias, QKb, Vt, nullptr,
        E, E, E, 2048, 0, 0, 0, 1.0f);

    // 3) Pu = exp(Q @ K^T / 32) (bf16) + row sums l (fp32 atomics)
    mfma_nt<MODE_SCORES><<<dim3(S / 128, S / 128, B), 256, 0, stream>>>(
        QKb, QKb + 1024, nullptr, Pu, nullptr, l,
        E, 2048, 2048, S,
        (long)S * 2048, (long)S * 2048, (long)S * S * 2 /*bytes*/, 0.03125f);

    // 4) out1 = Pu / l  (fp32 attention weights)
    normalize_rows<<<B * S, 256, 0, stream>>>(Pu, l, out1);

    // 5) out0 = (Pu @ V) / l
    mfma_nt<MODE_PV><<<dim3(E / 128, S / 128, B), 256, 0, stream>>>(
        Pu, Vt, nullptr, out0, nullptr, l,
        S, S, S, E,
        (long)S * S, (long)E * S, (long)S * E * 4 /*bytes*/, 1.0f);
}